// Round 5
// baseline (222.840 us; speedup 1.0000x reference)
//
#include <hip/hip_runtime.h>
#include <hip/hip_bf16.h>
#include <hip/hip_fp8.h>
#include <stdint.h>

#define P_B 4096
#define P_N 16384
#define P_F 768
#define P_E 512
#define NKT_F 24   // 768/32 k-tiles (bf16 packing, embed operands)
#define NKTP_E 8   // 512/64 k-tile-pairs (fp8 packing, echo operands)
#define CPAD 776   // convert LDS row pad (bf16 elems)
#define EPAD 136   // embed epilogue LDS row pad (bf16 elems)

typedef __attribute__((ext_vector_type(8))) __bf16 bf16x8;
typedef __attribute__((ext_vector_type(4))) float f32x4;

__device__ __forceinline__ unsigned short bfbits(float x) {
    __bf16 h = (__bf16)x;
    union { __bf16 h; unsigned short u; } cv;
    cv.h = h;
    return cv.u;
}
__device__ __forceinline__ float bf2f(unsigned short u) {
    union { float f; unsigned int i; } cv;
    cv.i = ((unsigned int)u) << 16;
    return cv.f;
}
__device__ __forceinline__ unsigned char f8bits(float x) {
    __hip_fp8_e4m3 h(x);           // OCP e4m3 on gfx950
    return (unsigned char)h.__x;
}

// bf16 fragment-packed (embed operands): element (r,k) ->
//   (((r>>4)*NKT_F + (k>>5))*64 + ((k>>3)&3)*16 + (r&15))*8 + (k&7)
// fp8 fragment-packed (echo operands), K grouped by 64 (two K=32 MFMA frags
// per 16B lane chunk): element (r,k) -> byte
//   (((r>>4)*NKTP_E + (k>>6))*64 + (((k>>3)&3)*16 + (r&15)))*16
//     + ((k>>5)&1)*8 + (k&7)

// ---------------------------------------------------------------------------
// Convert+pack (+ zero-init of norm2/echo): fp32 row-major -> bf16
// fragment-packed via LDS transpose. Blocks 0..255 = X, 256..1279 = D,
// 1280..1311 = gw.  (r6-proven)
// ---------------------------------------------------------------------------
__global__ __launch_bounds__(256) void convert_pack_kernel(
    const float* __restrict__ X, const float* __restrict__ D,
    const float* __restrict__ gw,
    unsigned short* __restrict__ xdpk, unsigned short* __restrict__ gwpk,
    float* __restrict__ zbase)   // norm2(20480) | echo(4096)
{
    __shared__ unsigned short T[16 * CPAD];
    const int tid = threadIdx.x;
    const int rb = blockIdx.x;          // 0..1311

    if (rb < 97) {
        const int z = rb * 256 + tid;
        if (z < P_B + P_N + P_B) zbase[z] = 0.0f;
    }

    const float* src;
    unsigned short* dstbase;
    if (rb < 256)       { src = X  + (size_t)rb * 16 * P_F;          dstbase = xdpk + (size_t)rb * NKT_F * 512; }
    else if (rb < 1280) { src = D  + (size_t)(rb - 256) * 16 * P_F;  dstbase = xdpk + (size_t)rb * NKT_F * 512; }
    else                { src = gw + (size_t)(rb - 1280) * 16 * P_F; dstbase = gwpk + (size_t)(rb - 1280) * NKT_F * 512; }

#pragma unroll
    for (int it = 0; it < 12; ++it) {
        const int flat = it * 1024 + tid * 4;
        const int row = flat / P_F;
        const int col = flat - row * P_F;
        const float4 v = *(const float4*)(src + (size_t)row * P_F + col);
        unsigned short* t = &T[row * CPAD + col];
        t[0] = bfbits(v.x); t[1] = bfbits(v.y); t[2] = bfbits(v.z); t[3] = bfbits(v.w);
    }
    __syncthreads();

#pragma unroll
    for (int it = 0; it < 6; ++it) {
        const int m = it * 256 + tid;
        const int kt = m >> 6;          // 0..23
        const int lane = m & 63;
        const int r = lane & 15;
        const int k = kt * 32 + (lane >> 4) * 8;
        const uint4 frag = *(const uint4*)(&T[r * CPAD + k]);
        *(uint4*)(dstbase + (size_t)(kt * 64 + lane) * 8) = frag;
    }
}

// ---------------------------------------------------------------------------
// Embed (r6-proven structure): emb = xd·gw^T + gb, barrier-free bf16 K-loop.
// Epilogue: bf16 LDS stash -> fp8 e4m3 conversion at read-out -> coalesced
// 16B packed stores (fp8 echo-operand layout) + per-row sum-of-squares.
// ---------------------------------------------------------------------------
__global__ __launch_bounds__(256, 2) void embed_pk_kernel(
    const unsigned short* __restrict__ xdpk, const unsigned short* __restrict__ gwpk,
    const float* __restrict__ gb,
    unsigned char* __restrict__ embpk8, float* __restrict__ norm2)
{
    __shared__ unsigned short Es[128 * EPAD];
    const int tid = threadIdx.x, lane = tid & 63, wave = tid >> 6;
    const int q = lane >> 4, c = lane & 15;
    const int colTile = blockIdx.x;   // 0..3
    const int rowTile = blockIdx.y;   // 0..159
    const int rbA0 = rowTile * 8 + (wave >> 1) * 4;
    const int rbB0 = colTile * 8 + (wave & 1) * 4;

    const unsigned short* pa[4];
    const unsigned short* pb[4];
#pragma unroll
    for (int i = 0; i < 4; i++)
        pa[i] = xdpk + ((size_t)(rbA0 + i) * NKT_F * 64 + lane) * 8;
#pragma unroll
    for (int j = 0; j < 4; j++)
        pb[j] = gwpk + ((size_t)(rbB0 + j) * NKT_F * 64 + lane) * 8;

    f32x4 acc[4][4];
    const f32x4 zero = {0.f, 0.f, 0.f, 0.f};
#pragma unroll
    for (int i = 0; i < 4; i++)
#pragma unroll
        for (int j = 0; j < 4; j++) acc[i][j] = zero;

#pragma unroll
    for (int kt = 0; kt < NKT_F; ++kt) {
        bf16x8 af[4], bfr[4];
#pragma unroll
        for (int i = 0; i < 4; i++) af[i] = *(const bf16x8*)(pa[i] + (size_t)kt * 512);
#pragma unroll
        for (int j = 0; j < 4; j++) bfr[j] = *(const bf16x8*)(pb[j] + (size_t)kt * 512);
#pragma unroll
        for (int i = 0; i < 4; i++)
#pragma unroll
            for (int j = 0; j < 4; j++)
                acc[i][j] = __builtin_amdgcn_mfma_f32_16x16x32_bf16(af[i], bfr[j], acc[i][j], 0, 0, 0);
    }

    // epilogue: bias, ssq (bf16 values), bf16 LDS stash
    float ss[4][4];
#pragma unroll
    for (int i = 0; i < 4; i++)
#pragma unroll
        for (int r = 0; r < 4; r++) ss[i][r] = 0.f;
#pragma unroll
    for (int j = 0; j < 4; j++) {
        const int lcbase = (wave & 1) * 64 + j * 16 + c;
        const float bias = gb[colTile * 128 + lcbase];
#pragma unroll
        for (int i = 0; i < 4; i++) {
#pragma unroll
            for (int r = 0; r < 4; r++) {
                const int lr = (wave >> 1) * 64 + i * 16 + q * 4 + r;
                const float v = acc[i][j][r] + bias;
                const unsigned short hb = bfbits(v);
                Es[lr * EPAD + lcbase] = hb;
                const float vs = bf2f(hb);
                ss[i][r] = fmaf(vs, vs, ss[i][r]);
            }
        }
    }
#pragma unroll
    for (int i = 0; i < 4; i++)
#pragma unroll
        for (int r = 0; r < 4; r++) {
            float s = ss[i][r];
            s += __shfl_xor(s, 1);
            s += __shfl_xor(s, 2);
            s += __shfl_xor(s, 4);
            s += __shfl_xor(s, 8);
            ss[i][r] = s;
        }
    if (c == 0) {
#pragma unroll
        for (int i = 0; i < 4; i++)
#pragma unroll
            for (int r = 0; r < 4; r++) {
                const int rowg = rowTile * 128 + (wave >> 1) * 64 + i * 16 + q * 4 + r;
                atomicAdd(&norm2[rowg], ss[i][r]);
            }
    }
    __syncthreads();

    // fp8 packed store: 8 rbl x 2 ktp x 64 lanes x 16B = 1024 chunks, 4 iters.
    // lane2's 16 bytes = values (r2, k = ktp*64 + {q2*8..+7, 32+q2*8..+7}).
#pragma unroll
    for (int it = 0; it < 4; ++it) {
        const int m = it * 256 + tid;
        const int rbl = m >> 7;             // 0..7
        const int rest = m & 127;
        const int ktpl = rest >> 6;         // 0..1
        const int lane2 = rest & 63;
        const int r2 = lane2 & 15;
        const int q2 = lane2 >> 4;
        const int lr = rbl * 16 + r2;
        const unsigned short* e0 = &Es[lr * EPAD + ktpl * 64 + q2 * 8];
        const unsigned short* e1 = e0 + 32;
        union { unsigned char b[16]; uint4 v; } outw;
#pragma unroll
        for (int t = 0; t < 8; t++) outw.b[t]     = f8bits(bf2f(e0[t]));
#pragma unroll
        for (int t = 0; t < 8; t++) outw.b[8 + t] = f8bits(bf2f(e1[t]));
        const size_t rb = (size_t)(rowTile * 8 + rbl);
        const size_t ktp = (size_t)(colTile * 2 + ktpl);
        *(uint4*)(embpk8 + ((rb * NKTP_E + ktp) * 64 + lane2) * 16) = outw.v;
    }
}

// ---------------------------------------------------------------------------
// Finalize: norm2[i] -> inv_norm^3 (X rows), inv_norm^3 * (2r-1) (D rows)
// ---------------------------------------------------------------------------
__global__ void finalize_kernel(float* __restrict__ nf, const float* __restrict__ r)
{
    const int i = blockIdx.x * 256 + threadIdx.x;
    if (i >= P_B + P_N) return;
    float nrm = sqrtf(nf[i]);
    nrm = fmaxf(nrm, 1e-12f);
    const float inv = 1.0f / nrm;
    float w = inv * inv * inv;
    if (i >= P_B) {
        const float rv = r[i - P_B];
        w *= (2.0f * rv - 1.0f);
    }
    nf[i] = w;
}

// ---------------------------------------------------------------------------
// Echo (fp8, round-0 structure + spill-free 4-waves/SIMD):
// supertile mapping + barrier-free fragment K-loop on fp8 e4m3 operands.
// NEW vs r4: operand loads are 8-byte (`long`, the native MFMA operand)
// instead of 16-byte uint4 -> live operand regs 32->16, and 32-bit offsets
// from the uniform base (saddr-form loads, 1 VGPR/offset) -> frees ~24 regs.
// r4 missed the 128-reg (4-wave) budget by only ~8 regs (32.5 MB spill
// writes); this fits with margin.  Same addresses, same L1 bytes, no layout
// or epilogue changes.
// ---------------------------------------------------------------------------
__global__ __launch_bounds__(256, 4) void echo_pk_kernel(
    const unsigned char* __restrict__ embpk8, const float* __restrict__ fbuf,
    float* __restrict__ echo)
{
    const int tid = threadIdx.x, lane = tid & 63, wave = tid >> 6;
    const int q = lane >> 4, c = lane & 15;
    const int bid = blockIdx.x;          // 0..4095
    const int sb = bid >> 6, w = bid & 63;
    const int btile = (sb & 3) * 8 + (w & 7);    // 0..31
    const int ntile = (sb >> 2) * 8 + (w >> 3);  // 0..127
    const int row0 = btile * 128;
    const int col0 = ntile * 128;
    const int rbA0 = btile * 8 + (wave >> 1) * 4;
    const int rbB0 = 256 + ntile * 8 + (wave & 1) * 4;   // De rows start at rb 256

    int offA[4], offB[4];
#pragma unroll
    for (int i = 0; i < 4; i++) offA[i] = ((rbA0 + i) * (NKTP_E * 64) + lane) * 16;
#pragma unroll
    for (int j = 0; j < 4; j++) offB[j] = ((rbB0 + j) * (NKTP_E * 64) + lane) * 16;

    f32x4 acc[4][4];
    const f32x4 zero = {0.f, 0.f, 0.f, 0.f};
#pragma unroll
    for (int i = 0; i < 4; i++)
#pragma unroll
        for (int j = 0; j < 4; j++) acc[i][j] = zero;

#pragma unroll
    for (int ktp = 0; ktp < NKTP_E; ++ktp) {
#pragma unroll
        for (int h = 0; h < 2; h++) {
            long ua[4], ub[4];
#pragma unroll
            for (int i = 0; i < 4; i++)
                ua[i] = *(const long*)(embpk8 + (offA[i] + ktp * 1024 + h * 8));
#pragma unroll
            for (int j = 0; j < 4; j++)
                ub[j] = *(const long*)(embpk8 + (offB[j] + ktp * 1024 + h * 8));
#pragma unroll
            for (int i = 0; i < 4; i++)
#pragma unroll
                for (int j = 0; j < 4; j++)
                    acc[i][j] = __builtin_amdgcn_mfma_f32_16x16x32_fp8_fp8(
                        ua[i], ub[j], acc[i][j], 0, 0, 0);
        }
    }

    // epilogue: cube, weight by (ind^3*r2), reduce over columns, atomicAdd rows
    const float* fX = fbuf;
    const float* fD = fbuf + P_B;
    float wc[4];
#pragma unroll
    for (int j = 0; j < 4; j++) wc[j] = fD[col0 + (wave & 1) * 64 + j * 16 + c];
    float p[4][4];
#pragma unroll
    for (int i = 0; i < 4; i++)
#pragma unroll
        for (int r = 0; r < 4; r++) p[i][r] = 0.f;
#pragma unroll
    for (int i = 0; i < 4; i++)
#pragma unroll
        for (int j = 0; j < 4; j++)
#pragma unroll
            for (int r = 0; r < 4; r++) {
                const float v = acc[i][j][r];
                const float v3 = v * v * v;
                p[i][r] = fmaf(v3, wc[j], p[i][r]);
            }
#pragma unroll
    for (int i = 0; i < 4; i++)
#pragma unroll
        for (int r = 0; r < 4; r++) {
            float s = p[i][r];
            s += __shfl_xor(s, 1);
            s += __shfl_xor(s, 2);
            s += __shfl_xor(s, 4);
            s += __shfl_xor(s, 8);
            p[i][r] = s;
        }
    if (c == 0) {
#pragma unroll
        for (int i = 0; i < 4; i++)
#pragma unroll
            for (int r = 0; r < 4; r++) {
                const int rowg = row0 + (wave >> 1) * 64 + i * 16 + q * 4 + r;
                atomicAdd(&echo[rowg], p[i][r] * fX[rowg]);
            }
    }
}

// ---------------------------------------------------------------------------
// Head: logits = echo*h_w + h_b ; preds = sigmoid(logits)
// ---------------------------------------------------------------------------
__global__ void head_kernel(const float* __restrict__ echo, const float* __restrict__ hw,
                            const float* __restrict__ hb, float* __restrict__ out)
{
    const int i = blockIdx.x * 256 + threadIdx.x;
    if (i >= P_B) return;
    const float logit = fmaf(echo[i], hw[0], hb[0]);
    out[i] = logit;
    out[P_B + i] = 1.0f / (1.0f + expf(-logit));
}

extern "C" void kernel_launch(void* const* d_in, const int* in_sizes, int n_in,
                              void* d_out, int out_size, void* d_ws, size_t ws_size,
                              hipStream_t stream)
{
    const float* X  = (const float*)d_in[0];
    const float* D  = (const float*)d_in[1];
    const float* r  = (const float*)d_in[2];
    const float* gw = (const float*)d_in[3];
    const float* gb = (const float*)d_in[4];
    const float* hw = (const float*)d_in[5];
    const float* hb = (const float*)d_in[6];
    float* out = (float*)d_out;

    char* ws = (char*)d_ws;
    const size_t xdpk_bytes   = (size_t)1280 * NKT_F * 64 * 8 * 2;    // 31,457,280
    const size_t gwpk_bytes   = (size_t)32 * NKT_F * 64 * 8 * 2;      //    786,432
    const size_t embpk8_bytes = (size_t)1280 * NKTP_E * 64 * 16;      // 10,485,760

    unsigned short* xdpk   = (unsigned short*)ws;
    unsigned short* gwpk   = (unsigned short*)(ws + xdpk_bytes);
    unsigned char*  embpk8 = (unsigned char*)(ws + xdpk_bytes + gwpk_bytes);
    float* norm2 = (float*)(ws + xdpk_bytes + gwpk_bytes + embpk8_bytes);
    float* echo = norm2 + (P_B + P_N);

    convert_pack_kernel<<<dim3(1312), 256, 0, stream>>>(X, D, gw, xdpk, gwpk, norm2);
    embed_pk_kernel<<<dim3(4, 160), 256, 0, stream>>>(xdpk, gwpk, gb, embpk8, norm2);
    finalize_kernel<<<dim3((P_B + P_N + 255) / 256), 256, 0, stream>>>(norm2, r);
    echo_pk_kernel<<<dim3(4096), 256, 0, stream>>>(embpk8, norm2, echo);
    head_kernel<<<dim3((P_B + 255) / 256), 256, 0, stream>>>(echo, hw, hb, out);
}

// Round 6
// 214.540 us; speedup vs baseline: 1.0387x; 1.0387x over previous
//
#include <hip/hip_runtime.h>
#include <hip/hip_bf16.h>
#include <hip/hip_fp8.h>
#include <stdint.h>

#define P_B 4096
#define P_N 16384
#define P_F 768
#define P_E 512
#define NKT_F 24   // 768/32 k-tiles (bf16 packing, embed operands)
#define NKTP_E 8   // 512/64 k-tile-pairs (fp8 packing, echo operands)
#define CPAD 776   // convert LDS row pad (bf16 elems)
#define EPAD 136   // embed epilogue LDS row pad (bf16 elems)

typedef __attribute__((ext_vector_type(8))) __bf16 bf16x8;
typedef __attribute__((ext_vector_type(4))) float f32x4;

__device__ __forceinline__ unsigned short bfbits(float x) {
    __bf16 h = (__bf16)x;
    union { __bf16 h; unsigned short u; } cv;
    cv.h = h;
    return cv.u;
}
__device__ __forceinline__ float bf2f(unsigned short u) {
    union { float f; unsigned int i; } cv;
    cv.i = ((unsigned int)u) << 16;
    return cv.f;
}
__device__ __forceinline__ unsigned char f8bits(float x) {
    __hip_fp8_e4m3 h(x);           // OCP e4m3 on gfx950
    return (unsigned char)h.__x;
}

// bf16 fragment-packed (embed operands): element (r,k) ->
//   (((r>>4)*NKT_F + (k>>5))*64 + ((k>>3)&3)*16 + (r&15))*8 + (k&7)
// fp8 fragment-packed (echo operands), K grouped by 64 (two K=32 MFMA frags
// per 16B lane chunk): element (r,k) -> byte
//   (((r>>4)*NKTP_E + (k>>6))*64 + (((k>>3)&3)*16 + (r&15)))*16
//     + ((k>>5)&1)*8 + (k&7)

// ---------------------------------------------------------------------------
// Convert+pack (+ zero-init of norm2/echo): fp32 row-major -> bf16
// fragment-packed via LDS transpose. Blocks 0..255 = X, 256..1279 = D,
// 1280..1311 = gw.  (r6-proven)
// ---------------------------------------------------------------------------
__global__ __launch_bounds__(256) void convert_pack_kernel(
    const float* __restrict__ X, const float* __restrict__ D,
    const float* __restrict__ gw,
    unsigned short* __restrict__ xdpk, unsigned short* __restrict__ gwpk,
    float* __restrict__ zbase)   // norm2(20480) | echo(4096)
{
    __shared__ unsigned short T[16 * CPAD];
    const int tid = threadIdx.x;
    const int rb = blockIdx.x;          // 0..1311

    if (rb < 97) {
        const int z = rb * 256 + tid;
        if (z < P_B + P_N + P_B) zbase[z] = 0.0f;
    }

    const float* src;
    unsigned short* dstbase;
    if (rb < 256)       { src = X  + (size_t)rb * 16 * P_F;          dstbase = xdpk + (size_t)rb * NKT_F * 512; }
    else if (rb < 1280) { src = D  + (size_t)(rb - 256) * 16 * P_F;  dstbase = xdpk + (size_t)rb * NKT_F * 512; }
    else                { src = gw + (size_t)(rb - 1280) * 16 * P_F; dstbase = gwpk + (size_t)(rb - 1280) * NKT_F * 512; }

#pragma unroll
    for (int it = 0; it < 12; ++it) {
        const int flat = it * 1024 + tid * 4;
        const int row = flat / P_F;
        const int col = flat - row * P_F;
        const float4 v = *(const float4*)(src + (size_t)row * P_F + col);
        unsigned short* t = &T[row * CPAD + col];
        t[0] = bfbits(v.x); t[1] = bfbits(v.y); t[2] = bfbits(v.z); t[3] = bfbits(v.w);
    }
    __syncthreads();

#pragma unroll
    for (int it = 0; it < 6; ++it) {
        const int m = it * 256 + tid;
        const int kt = m >> 6;          // 0..23
        const int lane = m & 63;
        const int r = lane & 15;
        const int k = kt * 32 + (lane >> 4) * 8;
        const uint4 frag = *(const uint4*)(&T[r * CPAD + k]);
        *(uint4*)(dstbase + (size_t)(kt * 64 + lane) * 8) = frag;
    }
}

// ---------------------------------------------------------------------------
// Embed (r6-proven structure): emb = xd·gw^T + gb, barrier-free bf16 K-loop.
// Epilogue: bf16 LDS stash -> fp8 e4m3 conversion at read-out -> coalesced
// 16B packed stores (fp8 echo-operand layout) + per-row sum-of-squares.
// ---------------------------------------------------------------------------
__global__ __launch_bounds__(256, 2) void embed_pk_kernel(
    const unsigned short* __restrict__ xdpk, const unsigned short* __restrict__ gwpk,
    const float* __restrict__ gb,
    unsigned char* __restrict__ embpk8, float* __restrict__ norm2)
{
    __shared__ unsigned short Es[128 * EPAD];
    const int tid = threadIdx.x, lane = tid & 63, wave = tid >> 6;
    const int q = lane >> 4, c = lane & 15;
    const int colTile = blockIdx.x;   // 0..3
    const int rowTile = blockIdx.y;   // 0..159
    const int rbA0 = rowTile * 8 + (wave >> 1) * 4;
    const int rbB0 = colTile * 8 + (wave & 1) * 4;

    const unsigned short* pa[4];
    const unsigned short* pb[4];
#pragma unroll
    for (int i = 0; i < 4; i++)
        pa[i] = xdpk + ((size_t)(rbA0 + i) * NKT_F * 64 + lane) * 8;
#pragma unroll
    for (int j = 0; j < 4; j++)
        pb[j] = gwpk + ((size_t)(rbB0 + j) * NKT_F * 64 + lane) * 8;

    f32x4 acc[4][4];
    const f32x4 zero = {0.f, 0.f, 0.f, 0.f};
#pragma unroll
    for (int i = 0; i < 4; i++)
#pragma unroll
        for (int j = 0; j < 4; j++) acc[i][j] = zero;

#pragma unroll
    for (int kt = 0; kt < NKT_F; ++kt) {
        bf16x8 af[4], bfr[4];
#pragma unroll
        for (int i = 0; i < 4; i++) af[i] = *(const bf16x8*)(pa[i] + (size_t)kt * 512);
#pragma unroll
        for (int j = 0; j < 4; j++) bfr[j] = *(const bf16x8*)(pb[j] + (size_t)kt * 512);
#pragma unroll
        for (int i = 0; i < 4; i++)
#pragma unroll
            for (int j = 0; j < 4; j++)
                acc[i][j] = __builtin_amdgcn_mfma_f32_16x16x32_bf16(af[i], bfr[j], acc[i][j], 0, 0, 0);
    }

    // epilogue: bias, ssq (bf16 values), bf16 LDS stash
    float ss[4][4];
#pragma unroll
    for (int i = 0; i < 4; i++)
#pragma unroll
        for (int r = 0; r < 4; r++) ss[i][r] = 0.f;
#pragma unroll
    for (int j = 0; j < 4; j++) {
        const int lcbase = (wave & 1) * 64 + j * 16 + c;
        const float bias = gb[colTile * 128 + lcbase];
#pragma unroll
        for (int i = 0; i < 4; i++) {
#pragma unroll
            for (int r = 0; r < 4; r++) {
                const int lr = (wave >> 1) * 64 + i * 16 + q * 4 + r;
                const float v = acc[i][j][r] + bias;
                const unsigned short hb = bfbits(v);
                Es[lr * EPAD + lcbase] = hb;
                const float vs = bf2f(hb);
                ss[i][r] = fmaf(vs, vs, ss[i][r]);
            }
        }
    }
#pragma unroll
    for (int i = 0; i < 4; i++)
#pragma unroll
        for (int r = 0; r < 4; r++) {
            float s = ss[i][r];
            s += __shfl_xor(s, 1);
            s += __shfl_xor(s, 2);
            s += __shfl_xor(s, 4);
            s += __shfl_xor(s, 8);
            ss[i][r] = s;
        }
    if (c == 0) {
#pragma unroll
        for (int i = 0; i < 4; i++)
#pragma unroll
            for (int r = 0; r < 4; r++) {
                const int rowg = rowTile * 128 + (wave >> 1) * 64 + i * 16 + q * 4 + r;
                atomicAdd(&norm2[rowg], ss[i][r]);
            }
    }
    __syncthreads();

    // fp8 packed store: 8 rbl x 2 ktp x 64 lanes x 16B = 1024 chunks, 4 iters.
    // lane2's 16 bytes = values (r2, k = ktp*64 + {q2*8..+7, 32+q2*8..+7}).
#pragma unroll
    for (int it = 0; it < 4; ++it) {
        const int m = it * 256 + tid;
        const int rbl = m >> 7;             // 0..7
        const int rest = m & 127;
        const int ktpl = rest >> 6;         // 0..1
        const int lane2 = rest & 63;
        const int r2 = lane2 & 15;
        const int q2 = lane2 >> 4;
        const int lr = rbl * 16 + r2;
        const unsigned short* e0 = &Es[lr * EPAD + ktpl * 64 + q2 * 8];
        const unsigned short* e1 = e0 + 32;
        union { unsigned char b[16]; uint4 v; } outw;
#pragma unroll
        for (int t = 0; t < 8; t++) outw.b[t]     = f8bits(bf2f(e0[t]));
#pragma unroll
        for (int t = 0; t < 8; t++) outw.b[8 + t] = f8bits(bf2f(e1[t]));
        const size_t rb = (size_t)(rowTile * 8 + rbl);
        const size_t ktp = (size_t)(colTile * 2 + ktpl);
        *(uint4*)(embpk8 + ((rb * NKTP_E + ktp) * 64 + lane2) * 16) = outw.v;
    }
}

// ---------------------------------------------------------------------------
// Finalize: norm2[i] -> inv_norm^3 (X rows), inv_norm^3 * (2r-1) (D rows)
// ---------------------------------------------------------------------------
__global__ void finalize_kernel(float* __restrict__ nf, const float* __restrict__ r)
{
    const int i = blockIdx.x * 256 + threadIdx.x;
    if (i >= P_B + P_N) return;
    float nrm = sqrtf(nf[i]);
    nrm = fmaxf(nrm, 1e-12f);
    const float inv = 1.0f / nrm;
    float w = inv * inv * inv;
    if (i >= P_B) {
        const float rv = r[i - P_B];
        w *= (2.0f * rv - 1.0f);
    }
    nf[i] = w;
}

// ---------------------------------------------------------------------------
// Echo (fp8, r0 structure + 16KB double-buffered LDS B-stage):
// supertile mapping + fragment K-loop on fp8 e4m3 operands, natural register
// budget (256,2).  NEW vs r0: per-ktp the block's 8 KB B panel is DMA'd to
// LDS (global_load_lds w16, 8 chunks, 2/wave), double-buffered: issue DMA
// for ktp+1, compute ktp (A from global vm pipe, B via ds_read_b128 from
// LDS lgkm pipe), barrier, swap.  vs r2 (full 64KB stage, 2 blocks/CU,
// serial prologue): LDS 16KB keeps 3 blocks/CU and staging overlaps MFMA.
// Block-level vm instrs/ktp: 32 -> 24; B-frag latency moves to LDS.
// ---------------------------------------------------------------------------
__global__ __launch_bounds__(256, 2) void echo_pk_kernel(
    const unsigned char* __restrict__ embpk8, const float* __restrict__ fbuf,
    float* __restrict__ echo)
{
    __shared__ unsigned char Bs[2][8 * 1024];   // per-ktp B panel, dbuf
    const int tid = threadIdx.x, lane = tid & 63, wave = tid >> 6;
    const int q = lane >> 4, c = lane & 15;
    const int bid = blockIdx.x;          // 0..4095
    const int sb = bid >> 6, w = bid & 63;
    const int btile = (sb & 3) * 8 + (w & 7);    // 0..31
    const int ntile = (sb >> 2) * 8 + (w >> 3);  // 0..127
    const int row0 = btile * 128;
    const int col0 = ntile * 128;
    const int rbA0 = btile * 8 + (wave >> 1) * 4;
    const int rbB0g = 256 + ntile * 8;           // De rows start at rb 256

    const unsigned char* gB = embpk8 + (size_t)rbB0g * (NKTP_E * 64 * 16);

    const unsigned char* pa[4];
#pragma unroll
    for (int i = 0; i < 4; i++)
        pa[i] = embpk8 + ((size_t)(rbA0 + i) * NKTP_E * 64 + lane) * 16;

    f32x4 acc[4][4];
    const f32x4 zero = {0.f, 0.f, 0.f, 0.f};
#pragma unroll
    for (int i = 0; i < 4; i++)
#pragma unroll
        for (int j = 0; j < 4; j++) acc[i][j] = zero;

    // prologue: stage ktp=0 into buf 0 (each wave DMAs 2 of 8 1KB chunks)
#pragma unroll
    for (int s = 0; s < 2; ++s) {
        const int chunk = wave * 2 + s;          // = rb_local 0..7
        const unsigned char* g = gB + (size_t)chunk * (NKTP_E * 1024) + (size_t)lane * 16;
        __builtin_amdgcn_global_load_lds(
            (const __attribute__((address_space(1))) unsigned int*)g,
            (__attribute__((address_space(3))) unsigned int*)(&Bs[0][chunk * 1024]),
            16, 0, 0);
    }
    __syncthreads();   // drains DMA: buf0 ready

#pragma unroll
    for (int ktp = 0; ktp < NKTP_E; ++ktp) {
        const int buf = ktp & 1;
        // issue DMA for next ktp into the other buffer (overlaps compute)
        if (ktp + 1 < NKTP_E) {
#pragma unroll
            for (int s = 0; s < 2; ++s) {
                const int chunk = wave * 2 + s;
                const unsigned char* g = gB + (size_t)chunk * (NKTP_E * 1024)
                                            + (size_t)(ktp + 1) * 1024 + (size_t)lane * 16;
                __builtin_amdgcn_global_load_lds(
                    (const __attribute__((address_space(1))) unsigned int*)g,
                    (__attribute__((address_space(3))) unsigned int*)(&Bs[buf ^ 1][chunk * 1024]),
                    16, 0, 0);
            }
        }
        union { uint4 v; long l[2]; } ua[4], ub[4];
#pragma unroll
        for (int i = 0; i < 4; i++) ua[i].v = *(const uint4*)(pa[i] + (size_t)ktp * 1024);
#pragma unroll
        for (int j = 0; j < 4; j++)
            ub[j].v = *(const uint4*)(&Bs[buf][(((wave & 1) * 4 + j) * 64 + lane) * 16]);
#pragma unroll
        for (int h = 0; h < 2; h++)
#pragma unroll
            for (int i = 0; i < 4; i++)
#pragma unroll
                for (int j = 0; j < 4; j++)
                    acc[i][j] = __builtin_amdgcn_mfma_f32_16x16x32_fp8_fp8(
                        ua[i].l[h], ub[j].l[h], acc[i][j], 0, 0, 0);
        __syncthreads();   // next buffer fully written; all waves done reading buf
    }

    // epilogue: cube, weight by (ind^3*r2), reduce over columns, atomicAdd rows
    const float* fX = fbuf;
    const float* fD = fbuf + P_B;
    float wc[4];
#pragma unroll
    for (int j = 0; j < 4; j++) wc[j] = fD[col0 + (wave & 1) * 64 + j * 16 + c];
    float p[4][4];
#pragma unroll
    for (int i = 0; i < 4; i++)
#pragma unroll
        for (int r = 0; r < 4; r++) p[i][r] = 0.f;
#pragma unroll
    for (int i = 0; i < 4; i++)
#pragma unroll
        for (int j = 0; j < 4; j++)
#pragma unroll
            for (int r = 0; r < 4; r++) {
                const float v = acc[i][j][r];
                const float v3 = v * v * v;
                p[i][r] = fmaf(v3, wc[j], p[i][r]);
            }
#pragma unroll
    for (int i = 0; i < 4; i++)
#pragma unroll
        for (int r = 0; r < 4; r++) {
            float s = p[i][r];
            s += __shfl_xor(s, 1);
            s += __shfl_xor(s, 2);
            s += __shfl_xor(s, 4);
            s += __shfl_xor(s, 8);
            p[i][r] = s;
        }
    if (c == 0) {
#pragma unroll
        for (int i = 0; i < 4; i++)
#pragma unroll
            for (int r = 0; r < 4; r++) {
                const int rowg = row0 + (wave >> 1) * 64 + i * 16 + q * 4 + r;
                atomicAdd(&echo[rowg], p[i][r] * fX[rowg]);
            }
    }
}

// ---------------------------------------------------------------------------
// Head: logits = echo*h_w + h_b ; preds = sigmoid(logits)
// ---------------------------------------------------------------------------
__global__ void head_kernel(const float* __restrict__ echo, const float* __restrict__ hw,
                            const float* __restrict__ hb, float* __restrict__ out)
{
    const int i = blockIdx.x * 256 + threadIdx.x;
    if (i >= P_B) return;
    const float logit = fmaf(echo[i], hw[0], hb[0]);
    out[i] = logit;
    out[P_B + i] = 1.0f / (1.0f + expf(-logit));
}

extern "C" void kernel_launch(void* const* d_in, const int* in_sizes, int n_in,
                              void* d_out, int out_size, void* d_ws, size_t ws_size,
                              hipStream_t stream)
{
    const float* X  = (const float*)d_in[0];
    const float* D  = (const float*)d_in[1];
    const float* r  = (const float*)d_in[2];
    const float* gw = (const float*)d_in[3];
    const float* gb = (const float*)d_in[4];
    const float* hw = (const float*)d_in[5];
    const float* hb = (const float*)d_in[6];
    float* out = (float*)d_out;

    char* ws = (char*)d_ws;
    const size_t xdpk_bytes   = (size_t)1280 * NKT_F * 64 * 8 * 2;    // 31,457,280
    const size_t gwpk_bytes   = (size_t)32 * NKT_F * 64 * 8 * 2;      //    786,432
    const size_t embpk8_bytes = (size_t)1280 * NKTP_E * 64 * 16;      // 10,485,760

    unsigned short* xdpk   = (unsigned short*)ws;
    unsigned short* gwpk   = (unsigned short*)(ws + xdpk_bytes);
    unsigned char*  embpk8 = (unsigned char*)(ws + xdpk_bytes + gwpk_bytes);
    float* norm2 = (float*)(ws + xdpk_bytes + gwpk_bytes + embpk8_bytes);
    float* echo = norm2 + (P_B + P_N);

    convert_pack_kernel<<<dim3(1312), 256, 0, stream>>>(X, D, gw, xdpk, gwpk, norm2);
    embed_pk_kernel<<<dim3(4, 160), 256, 0, stream>>>(xdpk, gwpk, gb, embpk8, norm2);
    finalize_kernel<<<dim3((P_B + P_N + 255) / 256), 256, 0, stream>>>(norm2, r);
    echo_pk_kernel<<<dim3(4096), 256, 0, stream>>>(embpk8, norm2, echo);
    head_kernel<<<dim3((P_B + 255) / 256), 256, 0, stream>>>(echo, hw, hb, out);
}

// Round 7
// 211.938 us; speedup vs baseline: 1.0514x; 1.0123x over previous
//
#include <hip/hip_runtime.h>
#include <hip/hip_bf16.h>
#include <hip/hip_fp8.h>
#include <stdint.h>

#define P_B 4096
#define P_N 16384
#define P_F 768
#define P_E 512
#define NKT_F 24   // 768/32 k-tiles (bf16 packing, embed operands)
#define NKTP_E 8   // 512/64 k-tile-pairs (fp8 packing, echo operands)
#define CPAD 776   // convert LDS row pad (bf16 elems)
#define EPAD2 72   // embed 64x64 epilogue LDS row pad (bf16 elems)

typedef __attribute__((ext_vector_type(8))) __bf16 bf16x8;
typedef __attribute__((ext_vector_type(4))) float f32x4;

__device__ __forceinline__ unsigned short bfbits(float x) {
    __bf16 h = (__bf16)x;
    union { __bf16 h; unsigned short u; } cv;
    cv.h = h;
    return cv.u;
}
__device__ __forceinline__ float bf2f(unsigned short u) {
    union { float f; unsigned int i; } cv;
    cv.i = ((unsigned int)u) << 16;
    return cv.f;
}
__device__ __forceinline__ unsigned char f8bits(float x) {
    __hip_fp8_e4m3 h(x);           // OCP e4m3 on gfx950
    return (unsigned char)h.__x;
}

// bf16 fragment-packed (embed operands): element (r,k) ->
//   (((r>>4)*NKT_F + (k>>5))*64 + ((k>>3)&3)*16 + (r&15))*8 + (k&7)
// fp8 fragment-packed (echo operands), K grouped by 64 (two K=32 MFMA frags
// per 16B lane chunk): element (r,k) -> byte
//   (((r>>4)*NKTP_E + (k>>6))*64 + (((k>>3)&3)*16 + (r&15)))*16
//     + ((k>>5)&1)*8 + (k&7)

// ---------------------------------------------------------------------------
// Convert+pack (+ zero-init of norm2/echo): fp32 row-major -> bf16
// fragment-packed via LDS transpose. Blocks 0..255 = X, 256..1279 = D,
// 1280..1311 = gw.  (r6-proven)
// ---------------------------------------------------------------------------
__global__ __launch_bounds__(256) void convert_pack_kernel(
    const float* __restrict__ X, const float* __restrict__ D,
    const float* __restrict__ gw,
    unsigned short* __restrict__ xdpk, unsigned short* __restrict__ gwpk,
    float* __restrict__ zbase)   // norm2(20480) | echo(4096)
{
    __shared__ unsigned short T[16 * CPAD];
    const int tid = threadIdx.x;
    const int rb = blockIdx.x;          // 0..1311

    if (rb < 97) {
        const int z = rb * 256 + tid;
        if (z < P_B + P_N + P_B) zbase[z] = 0.0f;
    }

    const float* src;
    unsigned short* dstbase;
    if (rb < 256)       { src = X  + (size_t)rb * 16 * P_F;          dstbase = xdpk + (size_t)rb * NKT_F * 512; }
    else if (rb < 1280) { src = D  + (size_t)(rb - 256) * 16 * P_F;  dstbase = xdpk + (size_t)rb * NKT_F * 512; }
    else                { src = gw + (size_t)(rb - 1280) * 16 * P_F; dstbase = gwpk + (size_t)(rb - 1280) * NKT_F * 512; }

#pragma unroll
    for (int it = 0; it < 12; ++it) {
        const int flat = it * 1024 + tid * 4;
        const int row = flat / P_F;
        const int col = flat - row * P_F;
        const float4 v = *(const float4*)(src + (size_t)row * P_F + col);
        unsigned short* t = &T[row * CPAD + col];
        t[0] = bfbits(v.x); t[1] = bfbits(v.y); t[2] = bfbits(v.z); t[3] = bfbits(v.w);
    }
    __syncthreads();

#pragma unroll
    for (int it = 0; it < 6; ++it) {
        const int m = it * 256 + tid;
        const int kt = m >> 6;          // 0..23
        const int lane = m & 63;
        const int r = lane & 15;
        const int k = kt * 32 + (lane >> 4) * 8;
        const uint4 frag = *(const uint4*)(&T[r * CPAD + k]);
        *(uint4*)(dstbase + (size_t)(kt * 64 + lane) * 8) = frag;
    }
}

// ---------------------------------------------------------------------------
// Embed (1-wave workgroups): emb = xd·gw^T + gb.  Each 64-thread block
// computes one independent 64x64 tile (acc 4x4, K=24 kt) — byte-identical
// per-wave work to the old 4-wave/128x128 version, but grid 640 -> 2560:
// 10 balanced wg/CU (was 2.5 blocks/CU, 20% tail), no inter-wave barrier
// coupling, ~12 independent waves/CU resident.  Epilogue: private LDS
// stash -> fp8 e4m3 -> coalesced 16B packed stores (ktp == colTile) +
// per-row sum-of-squares atomics.
// ---------------------------------------------------------------------------
__global__ __launch_bounds__(64) void embed_pk_kernel(
    const unsigned short* __restrict__ xdpk, const unsigned short* __restrict__ gwpk,
    const float* __restrict__ gb,
    unsigned char* __restrict__ embpk8, float* __restrict__ norm2)
{
    __shared__ unsigned short Es[64 * EPAD2];
    const int lane = threadIdx.x & 63;
    const int q = lane >> 4, c = lane & 15;
    const int colTile = blockIdx.x;   // 0..7   (64 cols = one echo ktp)
    const int rowTile = blockIdx.y;   // 0..319 (64 rows)
    const int rbA0 = rowTile * 4;
    const int rbB0 = colTile * 4;

    const unsigned short* pa[4];
    const unsigned short* pb[4];
#pragma unroll
    for (int i = 0; i < 4; i++)
        pa[i] = xdpk + ((size_t)(rbA0 + i) * NKT_F * 64 + lane) * 8;
#pragma unroll
    for (int j = 0; j < 4; j++)
        pb[j] = gwpk + ((size_t)(rbB0 + j) * NKT_F * 64 + lane) * 8;

    f32x4 acc[4][4];
    const f32x4 zero = {0.f, 0.f, 0.f, 0.f};
#pragma unroll
    for (int i = 0; i < 4; i++)
#pragma unroll
        for (int j = 0; j < 4; j++) acc[i][j] = zero;

#pragma unroll
    for (int kt = 0; kt < NKT_F; ++kt) {
        bf16x8 af[4], bfr[4];
#pragma unroll
        for (int i = 0; i < 4; i++) af[i] = *(const bf16x8*)(pa[i] + (size_t)kt * 512);
#pragma unroll
        for (int j = 0; j < 4; j++) bfr[j] = *(const bf16x8*)(pb[j] + (size_t)kt * 512);
#pragma unroll
        for (int i = 0; i < 4; i++)
#pragma unroll
            for (int j = 0; j < 4; j++)
                acc[i][j] = __builtin_amdgcn_mfma_f32_16x16x32_bf16(af[i], bfr[j], acc[i][j], 0, 0, 0);
    }

    // epilogue: bias, ssq (bf16 values), bf16 LDS stash (64x64 tile)
    float ss[4][4];
#pragma unroll
    for (int i = 0; i < 4; i++)
#pragma unroll
        for (int r = 0; r < 4; r++) ss[i][r] = 0.f;
#pragma unroll
    for (int j = 0; j < 4; j++) {
        const int lcbase = j * 16 + c;
        const float bias = gb[colTile * 64 + lcbase];
#pragma unroll
        for (int i = 0; i < 4; i++) {
#pragma unroll
            for (int r = 0; r < 4; r++) {
                const int lr = i * 16 + q * 4 + r;
                const float v = acc[i][j][r] + bias;
                const unsigned short hb = bfbits(v);
                Es[lr * EPAD2 + lcbase] = hb;
                const float vs = bf2f(hb);
                ss[i][r] = fmaf(vs, vs, ss[i][r]);
            }
        }
    }
#pragma unroll
    for (int i = 0; i < 4; i++)
#pragma unroll
        for (int r = 0; r < 4; r++) {
            float s = ss[i][r];
            s += __shfl_xor(s, 1);
            s += __shfl_xor(s, 2);
            s += __shfl_xor(s, 4);
            s += __shfl_xor(s, 8);
            ss[i][r] = s;
        }
    if (c == 0) {
#pragma unroll
        for (int i = 0; i < 4; i++)
#pragma unroll
            for (int r = 0; r < 4; r++) {
                const int rowg = rowTile * 64 + i * 16 + q * 4 + r;
                atomicAdd(&norm2[rowg], ss[i][r]);
            }
    }
    __syncthreads();

    // fp8 packed store: this tile's 64 cols are exactly ktp = colTile.
    // 4 rbl x 64 lanes x 16B = 4 coalesced 1KB stores.
#pragma unroll
    for (int rbl = 0; rbl < 4; ++rbl) {
        const int r2 = lane & 15;
        const int q2 = lane >> 4;
        const int lr = rbl * 16 + r2;
        const unsigned short* e0 = &Es[lr * EPAD2 + q2 * 8];
        const unsigned short* e1 = e0 + 32;
        union { unsigned char b[16]; uint4 v; } outw;
#pragma unroll
        for (int t = 0; t < 8; t++) outw.b[t]     = f8bits(bf2f(e0[t]));
#pragma unroll
        for (int t = 0; t < 8; t++) outw.b[8 + t] = f8bits(bf2f(e1[t]));
        const size_t rb = (size_t)(rowTile * 4 + rbl);
        const size_t ktp = (size_t)colTile;
        *(uint4*)(embpk8 + ((rb * NKTP_E + ktp) * 64 + lane) * 16) = outw.v;
    }
}

// ---------------------------------------------------------------------------
// Finalize: norm2[i] -> inv_norm^3 (X rows), inv_norm^3 * (2r-1) (D rows)
// ---------------------------------------------------------------------------
__global__ void finalize_kernel(float* __restrict__ nf, const float* __restrict__ r)
{
    const int i = blockIdx.x * 256 + threadIdx.x;
    if (i >= P_B + P_N) return;
    float nrm = sqrtf(nf[i]);
    nrm = fmaxf(nrm, 1e-12f);
    const float inv = 1.0f / nrm;
    float w = inv * inv * inv;
    if (i >= P_B) {
        const float rv = r[i - P_B];
        w *= (2.0f * rv - 1.0f);
    }
    nf[i] = w;
}

// ---------------------------------------------------------------------------
// Echo (fp8, r0-proven structure + setprio): supertile mapping +
// barrier-free fragment K-loop on fp8 e4m3 operands.  One dwordx4 per
// fragment-pair (K=64); two mfma_f32_16x16x32_fp8_fp8 per pair.  r1-r6
// established this macro-structure as the floor (six perturbations, six
// regressions).  NEW: s_setprio(1) around the MFMA cluster — waves here are
// barrier-free/independent (the attn-like regime where setprio measured
// +4-7%, not the lockstep regime where it nulls).
// ---------------------------------------------------------------------------
__global__ __launch_bounds__(256, 2) void echo_pk_kernel(
    const unsigned char* __restrict__ embpk8, const float* __restrict__ fbuf,
    float* __restrict__ echo)
{
    const int tid = threadIdx.x, lane = tid & 63, wave = tid >> 6;
    const int q = lane >> 4, c = lane & 15;
    const int bid = blockIdx.x;          // 0..4095
    const int sb = bid >> 6, w = bid & 63;
    const int btile = (sb & 3) * 8 + (w & 7);    // 0..31
    const int ntile = (sb >> 2) * 8 + (w >> 3);  // 0..127
    const int row0 = btile * 128;
    const int col0 = ntile * 128;
    const int rbA0 = btile * 8 + (wave >> 1) * 4;
    const int rbB0 = 256 + ntile * 8 + (wave & 1) * 4;   // De rows start at rb 256

    const unsigned char* pa[4];
    const unsigned char* pb[4];
#pragma unroll
    for (int i = 0; i < 4; i++)
        pa[i] = embpk8 + ((size_t)(rbA0 + i) * NKTP_E * 64 + lane) * 16;
#pragma unroll
    for (int j = 0; j < 4; j++)
        pb[j] = embpk8 + ((size_t)(rbB0 + j) * NKTP_E * 64 + lane) * 16;

    f32x4 acc[4][4];
    const f32x4 zero = {0.f, 0.f, 0.f, 0.f};
#pragma unroll
    for (int i = 0; i < 4; i++)
#pragma unroll
        for (int j = 0; j < 4; j++) acc[i][j] = zero;

#pragma unroll
    for (int ktp = 0; ktp < NKTP_E; ++ktp) {
        union { uint4 v; long l[2]; } ua[4], ub[4];
#pragma unroll
        for (int i = 0; i < 4; i++) ua[i].v = *(const uint4*)(pa[i] + (size_t)ktp * 1024);
#pragma unroll
        for (int j = 0; j < 4; j++) ub[j].v = *(const uint4*)(pb[j] + (size_t)ktp * 1024);
        __builtin_amdgcn_s_setprio(1);
#pragma unroll
        for (int h = 0; h < 2; h++)
#pragma unroll
            for (int i = 0; i < 4; i++)
#pragma unroll
                for (int j = 0; j < 4; j++)
                    acc[i][j] = __builtin_amdgcn_mfma_f32_16x16x32_fp8_fp8(
                        ua[i].l[h], ub[j].l[h], acc[i][j], 0, 0, 0);
        __builtin_amdgcn_s_setprio(0);
    }

    // epilogue: cube, weight by (ind^3*r2), reduce over columns, atomicAdd rows
    const float* fX = fbuf;
    const float* fD = fbuf + P_B;
    float wc[4];
#pragma unroll
    for (int j = 0; j < 4; j++) wc[j] = fD[col0 + (wave & 1) * 64 + j * 16 + c];
    float p[4][4];
#pragma unroll
    for (int i = 0; i < 4; i++)
#pragma unroll
        for (int r = 0; r < 4; r++) p[i][r] = 0.f;
#pragma unroll
    for (int i = 0; i < 4; i++)
#pragma unroll
        for (int j = 0; j < 4; j++)
#pragma unroll
            for (int r = 0; r < 4; r++) {
                const float v = acc[i][j][r];
                const float v3 = v * v * v;
                p[i][r] = fmaf(v3, wc[j], p[i][r]);
            }
#pragma unroll
    for (int i = 0; i < 4; i++)
#pragma unroll
        for (int r = 0; r < 4; r++) {
            float s = p[i][r];
            s += __shfl_xor(s, 1);
            s += __shfl_xor(s, 2);
            s += __shfl_xor(s, 4);
            s += __shfl_xor(s, 8);
            p[i][r] = s;
        }
    if (c == 0) {
#pragma unroll
        for (int i = 0; i < 4; i++)
#pragma unroll
            for (int r = 0; r < 4; r++) {
                const int rowg = row0 + (wave >> 1) * 64 + i * 16 + q * 4 + r;
                atomicAdd(&echo[rowg], p[i][r] * fX[rowg]);
            }
    }
}

// ---------------------------------------------------------------------------
// Head: logits = echo*h_w + h_b ; preds = sigmoid(logits)
// ---------------------------------------------------------------------------
__global__ void head_kernel(const float* __restrict__ echo, const float* __restrict__ hw,
                            const float* __restrict__ hb, float* __restrict__ out)
{
    const int i = blockIdx.x * 256 + threadIdx.x;
    if (i >= P_B) return;
    const float logit = fmaf(echo[i], hw[0], hb[0]);
    out[i] = logit;
    out[P_B + i] = 1.0f / (1.0f + expf(-logit));
}

extern "C" void kernel_launch(void* const* d_in, const int* in_sizes, int n_in,
                              void* d_out, int out_size, void* d_ws, size_t ws_size,
                              hipStream_t stream)
{
    const float* X  = (const float*)d_in[0];
    const float* D  = (const float*)d_in[1];
    const float* r  = (const float*)d_in[2];
    const float* gw = (const float*)d_in[3];
    const float* gb = (const float*)d_in[4];
    const float* hw = (const float*)d_in[5];
    const float* hb = (const float*)d_in[6];
    float* out = (float*)d_out;

    char* ws = (char*)d_ws;
    const size_t xdpk_bytes   = (size_t)1280 * NKT_F * 64 * 8 * 2;    // 31,457,280
    const size_t gwpk_bytes   = (size_t)32 * NKT_F * 64 * 8 * 2;      //    786,432
    const size_t embpk8_bytes = (size_t)1280 * NKTP_E * 64 * 16;      // 10,485,760

    unsigned short* xdpk   = (unsigned short*)ws;
    unsigned short* gwpk   = (unsigned short*)(ws + xdpk_bytes);
    unsigned char*  embpk8 = (unsigned char*)(ws + xdpk_bytes + gwpk_bytes);
    float* norm2 = (float*)(ws + xdpk_bytes + gwpk_bytes + embpk8_bytes);
    float* echo = norm2 + (P_B + P_N);

    convert_pack_kernel<<<dim3(1312), 256, 0, stream>>>(X, D, gw, xdpk, gwpk, norm2);
    embed_pk_kernel<<<dim3(8, 320), 64, 0, stream>>>(xdpk, gwpk, gb, embpk8, norm2);
    finalize_kernel<<<dim3((P_B + P_N + 255) / 256), 256, 0, stream>>>(norm2, r);
    echo_pk_kernel<<<dim3(4096), 256, 0, stream>>>(embpk8, norm2, echo);
    head_kernel<<<dim3((P_B + 255) / 256), 256, 0, stream>>>(echo, hw, hb, out);
}

// Round 8
// 192.158 us; speedup vs baseline: 1.1597x; 1.1029x over previous
//
#include <hip/hip_runtime.h>
#include <hip/hip_bf16.h>
#include <hip/hip_fp8.h>
#include <stdint.h>

#define P_B 4096
#define P_N 16384
#define P_F 768
#define P_E 512
#define NKT_F 24   // 768/32 k-tiles (bf16 packing, embed operands)
#define NKTP_E 8   // 512/64 k-tile-pairs (fp8 packing, echo operands)
#define CPAD 776   // convert LDS row pad (bf16 elems)
#define EPAD 136   // embed epilogue LDS row pad (bf16 elems)

typedef __attribute__((ext_vector_type(8))) __bf16 bf16x8;
typedef __attribute__((ext_vector_type(4))) float f32x4;

__device__ __forceinline__ unsigned short bfbits(float x) {
    __bf16 h = (__bf16)x;
    union { __bf16 h; unsigned short u; } cv;
    cv.h = h;
    return cv.u;
}
__device__ __forceinline__ float bf2f(unsigned short u) {
    union { float f; unsigned int i; } cv;
    cv.i = ((unsigned int)u) << 16;
    return cv.f;
}
__device__ __forceinline__ unsigned char f8bits(float x) {
    __hip_fp8_e4m3 h(x);           // OCP e4m3 on gfx950
    return (unsigned char)h.__x;
}

// bf16 fragment-packed (embed operands): element (r,k) ->
//   (((r>>4)*NKT_F + (k>>5))*64 + ((k>>3)&3)*16 + (r&15))*8 + (k&7)
// fp8 fragment-packed (echo operands), K grouped by 64 (two K=32 MFMA frags
// per 16B lane chunk): element (r,k) -> byte
//   (((r>>4)*NKTP_E + (k>>6))*64 + (((k>>3)&3)*16 + (r&15)))*16
//     + ((k>>5)&1)*8 + (k&7)

// ---------------------------------------------------------------------------
// Convert+pack (+ zero-init of norm2/echo): fp32 row-major -> bf16
// fragment-packed via LDS transpose. Blocks 0..255 = X, 256..1279 = D,
// 1280..1311 = gw.  (r6-proven)
// ---------------------------------------------------------------------------
__global__ __launch_bounds__(256) void convert_pack_kernel(
    const float* __restrict__ X, const float* __restrict__ D,
    const float* __restrict__ gw,
    unsigned short* __restrict__ xdpk, unsigned short* __restrict__ gwpk,
    float* __restrict__ zbase)   // norm2(20480) | echo(4096)
{
    __shared__ unsigned short T[16 * CPAD];
    const int tid = threadIdx.x;
    const int rb = blockIdx.x;          // 0..1311

    if (rb < 97) {
        const int z = rb * 256 + tid;
        if (z < P_B + P_N + P_B) zbase[z] = 0.0f;
    }

    const float* src;
    unsigned short* dstbase;
    if (rb < 256)       { src = X  + (size_t)rb * 16 * P_F;          dstbase = xdpk + (size_t)rb * NKT_F * 512; }
    else if (rb < 1280) { src = D  + (size_t)(rb - 256) * 16 * P_F;  dstbase = xdpk + (size_t)rb * NKT_F * 512; }
    else                { src = gw + (size_t)(rb - 1280) * 16 * P_F; dstbase = gwpk + (size_t)(rb - 1280) * NKT_F * 512; }

#pragma unroll
    for (int it = 0; it < 12; ++it) {
        const int flat = it * 1024 + tid * 4;
        const int row = flat / P_F;
        const int col = flat - row * P_F;
        const float4 v = *(const float4*)(src + (size_t)row * P_F + col);
        unsigned short* t = &T[row * CPAD + col];
        t[0] = bfbits(v.x); t[1] = bfbits(v.y); t[2] = bfbits(v.z); t[3] = bfbits(v.w);
    }
    __syncthreads();

#pragma unroll
    for (int it = 0; it < 6; ++it) {
        const int m = it * 256 + tid;
        const int kt = m >> 6;          // 0..23
        const int lane = m & 63;
        const int r = lane & 15;
        const int k = kt * 32 + (lane >> 4) * 8;
        const uint4 frag = *(const uint4*)(&T[r * CPAD + k]);
        *(uint4*)(dstbase + (size_t)(kt * 64 + lane) * 8) = frag;
    }
}

// ---------------------------------------------------------------------------
// Embed (r6-proven structure, r0 config): emb = xd·gw^T + gb, barrier-free
// bf16 K-loop, 4-wave 128x128 blocks, grid (4,160).  Epilogue: bf16 LDS
// stash -> fp8 e4m3 conversion at read-out -> coalesced 16B packed stores
// (fp8 echo-operand layout) + per-row sum-of-squares.  (r7's 1-wave variant
// regressed ~17 us -> reverted.)
// ---------------------------------------------------------------------------
__global__ __launch_bounds__(256, 2) void embed_pk_kernel(
    const unsigned short* __restrict__ xdpk, const unsigned short* __restrict__ gwpk,
    const float* __restrict__ gb,
    unsigned char* __restrict__ embpk8, float* __restrict__ norm2)
{
    __shared__ unsigned short Es[128 * EPAD];
    const int tid = threadIdx.x, lane = tid & 63, wave = tid >> 6;
    const int q = lane >> 4, c = lane & 15;
    const int colTile = blockIdx.x;   // 0..3
    const int rowTile = blockIdx.y;   // 0..159
    const int rbA0 = rowTile * 8 + (wave >> 1) * 4;
    const int rbB0 = colTile * 8 + (wave & 1) * 4;

    const unsigned short* pa[4];
    const unsigned short* pb[4];
#pragma unroll
    for (int i = 0; i < 4; i++)
        pa[i] = xdpk + ((size_t)(rbA0 + i) * NKT_F * 64 + lane) * 8;
#pragma unroll
    for (int j = 0; j < 4; j++)
        pb[j] = gwpk + ((size_t)(rbB0 + j) * NKT_F * 64 + lane) * 8;

    f32x4 acc[4][4];
    const f32x4 zero = {0.f, 0.f, 0.f, 0.f};
#pragma unroll
    for (int i = 0; i < 4; i++)
#pragma unroll
        for (int j = 0; j < 4; j++) acc[i][j] = zero;

#pragma unroll
    for (int kt = 0; kt < NKT_F; ++kt) {
        bf16x8 af[4], bfr[4];
#pragma unroll
        for (int i = 0; i < 4; i++) af[i] = *(const bf16x8*)(pa[i] + (size_t)kt * 512);
#pragma unroll
        for (int j = 0; j < 4; j++) bfr[j] = *(const bf16x8*)(pb[j] + (size_t)kt * 512);
#pragma unroll
        for (int i = 0; i < 4; i++)
#pragma unroll
            for (int j = 0; j < 4; j++)
                acc[i][j] = __builtin_amdgcn_mfma_f32_16x16x32_bf16(af[i], bfr[j], acc[i][j], 0, 0, 0);
    }

    // epilogue: bias, ssq (bf16 values), bf16 LDS stash
    float ss[4][4];
#pragma unroll
    for (int i = 0; i < 4; i++)
#pragma unroll
        for (int r = 0; r < 4; r++) ss[i][r] = 0.f;
#pragma unroll
    for (int j = 0; j < 4; j++) {
        const int lcbase = (wave & 1) * 64 + j * 16 + c;
        const float bias = gb[colTile * 128 + lcbase];
#pragma unroll
        for (int i = 0; i < 4; i++) {
#pragma unroll
            for (int r = 0; r < 4; r++) {
                const int lr = (wave >> 1) * 64 + i * 16 + q * 4 + r;
                const float v = acc[i][j][r] + bias;
                const unsigned short hb = bfbits(v);
                Es[lr * EPAD + lcbase] = hb;
                const float vs = bf2f(hb);
                ss[i][r] = fmaf(vs, vs, ss[i][r]);
            }
        }
    }
#pragma unroll
    for (int i = 0; i < 4; i++)
#pragma unroll
        for (int r = 0; r < 4; r++) {
            float s = ss[i][r];
            s += __shfl_xor(s, 1);
            s += __shfl_xor(s, 2);
            s += __shfl_xor(s, 4);
            s += __shfl_xor(s, 8);
            ss[i][r] = s;
        }
    if (c == 0) {
#pragma unroll
        for (int i = 0; i < 4; i++)
#pragma unroll
            for (int r = 0; r < 4; r++) {
                const int rowg = rowTile * 128 + (wave >> 1) * 64 + i * 16 + q * 4 + r;
                atomicAdd(&norm2[rowg], ss[i][r]);
            }
    }
    __syncthreads();

    // fp8 packed store: 8 rbl x 2 ktp x 64 lanes x 16B = 1024 chunks, 4 iters.
    // lane2's 16 bytes = values (r2, k = ktp*64 + {q2*8..+7, 32+q2*8..+7}).
#pragma unroll
    for (int it = 0; it < 4; ++it) {
        const int m = it * 256 + tid;
        const int rbl = m >> 7;             // 0..7
        const int rest = m & 127;
        const int ktpl = rest >> 6;         // 0..1
        const int lane2 = rest & 63;
        const int r2 = lane2 & 15;
        const int q2 = lane2 >> 4;
        const int lr = rbl * 16 + r2;
        const unsigned short* e0 = &Es[lr * EPAD + ktpl * 64 + q2 * 8];
        const unsigned short* e1 = e0 + 32;
        union { unsigned char b[16]; uint4 v; } outw;
#pragma unroll
        for (int t = 0; t < 8; t++) outw.b[t]     = f8bits(bf2f(e0[t]));
#pragma unroll
        for (int t = 0; t < 8; t++) outw.b[8 + t] = f8bits(bf2f(e1[t]));
        const size_t rb = (size_t)(rowTile * 8 + rbl);
        const size_t ktp = (size_t)(colTile * 2 + ktpl);
        *(uint4*)(embpk8 + ((rb * NKTP_E + ktp) * 64 + lane2) * 16) = outw.v;
    }
}

// ---------------------------------------------------------------------------
// Finalize: norm2[i] -> inv_norm^3 (X rows), inv_norm^3 * (2r-1) (D rows)
// ---------------------------------------------------------------------------
__global__ void finalize_kernel(float* __restrict__ nf, const float* __restrict__ r)
{
    const int i = blockIdx.x * 256 + threadIdx.x;
    if (i >= P_B + P_N) return;
    float nrm = sqrtf(nf[i]);
    nrm = fmaxf(nrm, 1e-12f);
    const float inv = 1.0f / nrm;
    float w = inv * inv * inv;
    if (i >= P_B) {
        const float rv = r[i - P_B];
        w *= (2.0f * rv - 1.0f);
    }
    nf[i] = w;
}

// ---------------------------------------------------------------------------
// Echo (fp8, r0-proven structure + setprio — r7-verified: 60.0 us,
// MfmaUtil 45%, VGPR 60 -> 124 unified regs -> 4 waves/SIMD, no spill).
// Supertile mapping + barrier-free fragment K-loop on fp8 e4m3 operands.
// One dwordx4 per fragment-pair (K=64); two mfma_f32_16x16x32_fp8_fp8 per
// pair.  s_setprio(1) around the MFMA cluster (independent-wave regime).
// ---------------------------------------------------------------------------
__global__ __launch_bounds__(256, 2) void echo_pk_kernel(
    const unsigned char* __restrict__ embpk8, const float* __restrict__ fbuf,
    float* __restrict__ echo)
{
    const int tid = threadIdx.x, lane = tid & 63, wave = tid >> 6;
    const int q = lane >> 4, c = lane & 15;
    const int bid = blockIdx.x;          // 0..4095
    const int sb = bid >> 6, w = bid & 63;
    const int btile = (sb & 3) * 8 + (w & 7);    // 0..31
    const int ntile = (sb >> 2) * 8 + (w >> 3);  // 0..127
    const int row0 = btile * 128;
    const int col0 = ntile * 128;
    const int rbA0 = btile * 8 + (wave >> 1) * 4;
    const int rbB0 = 256 + ntile * 8 + (wave & 1) * 4;   // De rows start at rb 256

    const unsigned char* pa[4];
    const unsigned char* pb[4];
#pragma unroll
    for (int i = 0; i < 4; i++)
        pa[i] = embpk8 + ((size_t)(rbA0 + i) * NKTP_E * 64 + lane) * 16;
#pragma unroll
    for (int j = 0; j < 4; j++)
        pb[j] = embpk8 + ((size_t)(rbB0 + j) * NKTP_E * 64 + lane) * 16;

    f32x4 acc[4][4];
    const f32x4 zero = {0.f, 0.f, 0.f, 0.f};
#pragma unroll
    for (int i = 0; i < 4; i++)
#pragma unroll
        for (int j = 0; j < 4; j++) acc[i][j] = zero;

#pragma unroll
    for (int ktp = 0; ktp < NKTP_E; ++ktp) {
        union { uint4 v; long l[2]; } ua[4], ub[4];
#pragma unroll
        for (int i = 0; i < 4; i++) ua[i].v = *(const uint4*)(pa[i] + (size_t)ktp * 1024);
#pragma unroll
        for (int j = 0; j < 4; j++) ub[j].v = *(const uint4*)(pb[j] + (size_t)ktp * 1024);
        __builtin_amdgcn_s_setprio(1);
#pragma unroll
        for (int h = 0; h < 2; h++)
#pragma unroll
            for (int i = 0; i < 4; i++)
#pragma unroll
                for (int j = 0; j < 4; j++)
                    acc[i][j] = __builtin_amdgcn_mfma_f32_16x16x32_fp8_fp8(
                        ua[i].l[h], ub[j].l[h], acc[i][j], 0, 0, 0);
        __builtin_amdgcn_s_setprio(0);
    }

    // epilogue: cube, weight by (ind^3*r2), reduce over columns, atomicAdd rows
    const float* fX = fbuf;
    const float* fD = fbuf + P_B;
    float wc[4];
#pragma unroll
    for (int j = 0; j < 4; j++) wc[j] = fD[col0 + (wave & 1) * 64 + j * 16 + c];
    float p[4][4];
#pragma unroll
    for (int i = 0; i < 4; i++)
#pragma unroll
        for (int r = 0; r < 4; r++) p[i][r] = 0.f;
#pragma unroll
    for (int i = 0; i < 4; i++)
#pragma unroll
        for (int j = 0; j < 4; j++)
#pragma unroll
            for (int r = 0; r < 4; r++) {
                const float v = acc[i][j][r];
                const float v3 = v * v * v;
                p[i][r] = fmaf(v3, wc[j], p[i][r]);
            }
#pragma unroll
    for (int i = 0; i < 4; i++)
#pragma unroll
        for (int r = 0; r < 4; r++) {
            float s = p[i][r];
            s += __shfl_xor(s, 1);
            s += __shfl_xor(s, 2);
            s += __shfl_xor(s, 4);
            s += __shfl_xor(s, 8);
            p[i][r] = s;
        }
    if (c == 0) {
#pragma unroll
        for (int i = 0; i < 4; i++)
#pragma unroll
            for (int r = 0; r < 4; r++) {
                const int rowg = row0 + (wave >> 1) * 64 + i * 16 + q * 4 + r;
                atomicAdd(&echo[rowg], p[i][r] * fX[rowg]);
            }
    }
}

// ---------------------------------------------------------------------------
// Head: logits = echo*h_w + h_b ; preds = sigmoid(logits)
// ---------------------------------------------------------------------------
__global__ void head_kernel(const float* __restrict__ echo, const float* __restrict__ hw,
                            const float* __restrict__ hb, float* __restrict__ out)
{
    const int i = blockIdx.x * 256 + threadIdx.x;
    if (i >= P_B) return;
    const float logit = fmaf(echo[i], hw[0], hb[0]);
    out[i] = logit;
    out[P_B + i] = 1.0f / (1.0f + expf(-logit));
}

extern "C" void kernel_launch(void* const* d_in, const int* in_sizes, int n_in,
                              void* d_out, int out_size, void* d_ws, size_t ws_size,
                              hipStream_t stream)
{
    const float* X  = (const float*)d_in[0];
    const float* D  = (const float*)d_in[1];
    const float* r  = (const float*)d_in[2];
    const float* gw = (const float*)d_in[3];
    const float* gb = (const float*)d_in[4];
    const float* hw = (const float*)d_in[5];
    const float* hb = (const float*)d_in[6];
    float* out = (float*)d_out;

    char* ws = (char*)d_ws;
    const size_t xdpk_bytes   = (size_t)1280 * NKT_F * 64 * 8 * 2;    // 31,457,280
    const size_t gwpk_bytes   = (size_t)32 * NKT_F * 64 * 8 * 2;      //    786,432
    const size_t embpk8_bytes = (size_t)1280 * NKTP_E * 64 * 16;      // 10,485,760

    unsigned short* xdpk   = (unsigned short*)ws;
    unsigned short* gwpk   = (unsigned short*)(ws + xdpk_bytes);
    unsigned char*  embpk8 = (unsigned char*)(ws + xdpk_bytes + gwpk_bytes);
    float* norm2 = (float*)(ws + xdpk_bytes + gwpk_bytes + embpk8_bytes);
    float* echo = norm2 + (P_B + P_N);

    convert_pack_kernel<<<dim3(1312), 256, 0, stream>>>(X, D, gw, xdpk, gwpk, norm2);
    embed_pk_kernel<<<dim3(4, 160), 256, 0, stream>>>(xdpk, gwpk, gb, embpk8, norm2);
    finalize_kernel<<<dim3((P_B + P_N + 255) / 256), 256, 0, stream>>>(norm2, r);
    echo_pk_kernel<<<dim3(4096), 256, 0, stream>>>(embpk8, norm2, echo);
    head_kernel<<<dim3((P_B + 255) / 256), 256, 0, stream>>>(echo, hw, hb, out);
}

// Round 9
// 188.333 us; speedup vs baseline: 1.1832x; 1.0203x over previous
//
#include <hip/hip_runtime.h>
#include <hip/hip_bf16.h>
#include <hip/hip_fp8.h>
#include <stdint.h>

#define P_B 4096
#define P_N 16384
#define P_F 768
#define P_E 512
#define NKT_F 24   // 768/32 k-tiles (bf16 packing, embed operands)
#define NKTP_E 8   // 512/64 k-tile-pairs (fp8 packing, echo operands)
#define CPAD 776   // convert LDS row pad (bf16 elems)
#define EPAD 136   // embed epilogue LDS row pad (bf16 elems)

typedef __attribute__((ext_vector_type(8))) __bf16 bf16x8;
typedef __attribute__((ext_vector_type(4))) float f32x4;

__device__ __forceinline__ unsigned short bfbits(float x) {
    __bf16 h = (__bf16)x;
    union { __bf16 h; unsigned short u; } cv;
    cv.h = h;
    return cv.u;
}
__device__ __forceinline__ float bf2f(unsigned short u) {
    union { float f; unsigned int i; } cv;
    cv.i = ((unsigned int)u) << 16;
    return cv.f;
}
__device__ __forceinline__ unsigned char f8bits(float x) {
    __hip_fp8_e4m3 h(x);           // OCP e4m3 on gfx950
    return (unsigned char)h.__x;
}

// bf16 fragment-packed (embed operands): element (r,k) ->
//   (((r>>4)*NKT_F + (k>>5))*64 + ((k>>3)&3)*16 + (r&15))*8 + (k&7)
// fp8 fragment-packed (echo operands), K grouped by 64 (two K=32 MFMA frags
// per 16B lane chunk): element (r,k) -> byte
//   (((r>>4)*NKTP_E + (k>>6))*64 + (((k>>3)&3)*16 + (r&15)))*16
//     + ((k>>5)&1)*8 + (k&7)

// ---------------------------------------------------------------------------
// Convert+pack (+ zero-init of norm2/echo): fp32 row-major -> bf16
// fragment-packed via LDS transpose. Blocks 0..255 = X, 256..1279 = D,
// 1280..1311 = gw.  (r6-proven)
// ---------------------------------------------------------------------------
__global__ __launch_bounds__(256) void convert_pack_kernel(
    const float* __restrict__ X, const float* __restrict__ D,
    const float* __restrict__ gw,
    unsigned short* __restrict__ xdpk, unsigned short* __restrict__ gwpk,
    float* __restrict__ zbase)   // norm2(20480) | echo(4096)
{
    __shared__ unsigned short T[16 * CPAD];
    const int tid = threadIdx.x;
    const int rb = blockIdx.x;          // 0..1311

    if (rb < 97) {
        const int z = rb * 256 + tid;
        if (z < P_B + P_N + P_B) zbase[z] = 0.0f;
    }

    const float* src;
    unsigned short* dstbase;
    if (rb < 256)       { src = X  + (size_t)rb * 16 * P_F;          dstbase = xdpk + (size_t)rb * NKT_F * 512; }
    else if (rb < 1280) { src = D  + (size_t)(rb - 256) * 16 * P_F;  dstbase = xdpk + (size_t)rb * NKT_F * 512; }
    else                { src = gw + (size_t)(rb - 1280) * 16 * P_F; dstbase = gwpk + (size_t)(rb - 1280) * NKT_F * 512; }

#pragma unroll
    for (int it = 0; it < 12; ++it) {
        const int flat = it * 1024 + tid * 4;
        const int row = flat / P_F;
        const int col = flat - row * P_F;
        const float4 v = *(const float4*)(src + (size_t)row * P_F + col);
        unsigned short* t = &T[row * CPAD + col];
        t[0] = bfbits(v.x); t[1] = bfbits(v.y); t[2] = bfbits(v.z); t[3] = bfbits(v.w);
    }
    __syncthreads();

#pragma unroll
    for (int it = 0; it < 6; ++it) {
        const int m = it * 256 + tid;
        const int kt = m >> 6;          // 0..23
        const int lane = m & 63;
        const int r = lane & 15;
        const int k = kt * 32 + (lane >> 4) * 8;
        const uint4 frag = *(const uint4*)(&T[r * CPAD + k]);
        *(uint4*)(dstbase + (size_t)(kt * 64 + lane) * 8) = frag;
    }
}

// ---------------------------------------------------------------------------
// Embed (r6-proven structure + XCD-affinity remap + setprio): emb = xd·gw^T
// + gb, barrier-free bf16 K-loop, 4-wave 128x128 blocks.  NEW vs r8:
// (1) in-kernel bijective remap so the 4 colTile blocks sharing a rowTile
// land on the SAME XCD (dispatch round-robins flat bid % 8): A-panel
// (196 KB/rowTile) is fetched from HBM once per XCD instead of 4x
// (126 MB -> ~32 MB); per-XCD L2 window ~3.9 MB fits.  Unlike r3's echo
// swizzle (64-CU same-address pileup), this is 4-way sharing for traffic
// dedup.  (2) s_setprio(1) around the MFMA cluster (r7-proven on the
// identical echo code shape).  Epilogue unchanged.
// ---------------------------------------------------------------------------
__global__ __launch_bounds__(256, 2) void embed_pk_kernel(
    const unsigned short* __restrict__ xdpk, const unsigned short* __restrict__ gwpk,
    const float* __restrict__ gb,
    unsigned char* __restrict__ embpk8, float* __restrict__ norm2)
{
    __shared__ unsigned short Es[128 * EPAD];
    const int tid = threadIdx.x, lane = tid & 63, wave = tid >> 6;
    const int q = lane >> 4, c = lane & 15;
    // XCD-affinity remap: flat dispatch id 0..639; xcd = flat & 7.
    // XCD x owns rowTiles [x*20, x*20+20), all 4 colTiles of each.
    const int flat = blockIdx.x + 4 * blockIdx.y;
    const int xcd = flat & 7;
    const int idx = flat >> 3;            // 0..79
    const int rowTile = xcd * 20 + (idx >> 2);   // 0..159
    const int colTile = idx & 3;                 // 0..3
    const int rbA0 = rowTile * 8 + (wave >> 1) * 4;
    const int rbB0 = colTile * 8 + (wave & 1) * 4;

    const unsigned short* pa[4];
    const unsigned short* pb[4];
#pragma unroll
    for (int i = 0; i < 4; i++)
        pa[i] = xdpk + ((size_t)(rbA0 + i) * NKT_F * 64 + lane) * 8;
#pragma unroll
    for (int j = 0; j < 4; j++)
        pb[j] = gwpk + ((size_t)(rbB0 + j) * NKT_F * 64 + lane) * 8;

    f32x4 acc[4][4];
    const f32x4 zero = {0.f, 0.f, 0.f, 0.f};
#pragma unroll
    for (int i = 0; i < 4; i++)
#pragma unroll
        for (int j = 0; j < 4; j++) acc[i][j] = zero;

#pragma unroll
    for (int kt = 0; kt < NKT_F; ++kt) {
        bf16x8 af[4], bfr[4];
#pragma unroll
        for (int i = 0; i < 4; i++) af[i] = *(const bf16x8*)(pa[i] + (size_t)kt * 512);
#pragma unroll
        for (int j = 0; j < 4; j++) bfr[j] = *(const bf16x8*)(pb[j] + (size_t)kt * 512);
        __builtin_amdgcn_s_setprio(1);
#pragma unroll
        for (int i = 0; i < 4; i++)
#pragma unroll
            for (int j = 0; j < 4; j++)
                acc[i][j] = __builtin_amdgcn_mfma_f32_16x16x32_bf16(af[i], bfr[j], acc[i][j], 0, 0, 0);
        __builtin_amdgcn_s_setprio(0);
    }

    // epilogue: bias, ssq (bf16 values), bf16 LDS stash
    float ss[4][4];
#pragma unroll
    for (int i = 0; i < 4; i++)
#pragma unroll
        for (int r = 0; r < 4; r++) ss[i][r] = 0.f;
#pragma unroll
    for (int j = 0; j < 4; j++) {
        const int lcbase = (wave & 1) * 64 + j * 16 + c;
        const float bias = gb[colTile * 128 + lcbase];
#pragma unroll
        for (int i = 0; i < 4; i++) {
#pragma unroll
            for (int r = 0; r < 4; r++) {
                const int lr = (wave >> 1) * 64 + i * 16 + q * 4 + r;
                const float v = acc[i][j][r] + bias;
                const unsigned short hb = bfbits(v);
                Es[lr * EPAD + lcbase] = hb;
                const float vs = bf2f(hb);
                ss[i][r] = fmaf(vs, vs, ss[i][r]);
            }
        }
    }
#pragma unroll
    for (int i = 0; i < 4; i++)
#pragma unroll
        for (int r = 0; r < 4; r++) {
            float s = ss[i][r];
            s += __shfl_xor(s, 1);
            s += __shfl_xor(s, 2);
            s += __shfl_xor(s, 4);
            s += __shfl_xor(s, 8);
            ss[i][r] = s;
        }
    if (c == 0) {
#pragma unroll
        for (int i = 0; i < 4; i++)
#pragma unroll
            for (int r = 0; r < 4; r++) {
                const int rowg = rowTile * 128 + (wave >> 1) * 64 + i * 16 + q * 4 + r;
                atomicAdd(&norm2[rowg], ss[i][r]);
            }
    }
    __syncthreads();

    // fp8 packed store: 8 rbl x 2 ktp x 64 lanes x 16B = 1024 chunks, 4 iters.
    // lane2's 16 bytes = values (r2, k = ktp*64 + {q2*8..+7, 32+q2*8..+7}).
#pragma unroll
    for (int it = 0; it < 4; ++it) {
        const int m = it * 256 + tid;
        const int rbl = m >> 7;             // 0..7
        const int rest = m & 127;
        const int ktpl = rest >> 6;         // 0..1
        const int lane2 = rest & 63;
        const int r2 = lane2 & 15;
        const int q2 = lane2 >> 4;
        const int lr = rbl * 16 + r2;
        const unsigned short* e0 = &Es[lr * EPAD + ktpl * 64 + q2 * 8];
        const unsigned short* e1 = e0 + 32;
        union { unsigned char b[16]; uint4 v; } outw;
#pragma unroll
        for (int t = 0; t < 8; t++) outw.b[t]     = f8bits(bf2f(e0[t]));
#pragma unroll
        for (int t = 0; t < 8; t++) outw.b[8 + t] = f8bits(bf2f(e1[t]));
        const size_t rb = (size_t)(rowTile * 8 + rbl);
        const size_t ktp = (size_t)(colTile * 2 + ktpl);
        *(uint4*)(embpk8 + ((rb * NKTP_E + ktp) * 64 + lane2) * 16) = outw.v;
    }
}

// ---------------------------------------------------------------------------
// Finalize: norm2[i] -> inv_norm^3 (X rows), inv_norm^3 * (2r-1) (D rows)
// ---------------------------------------------------------------------------
__global__ void finalize_kernel(float* __restrict__ nf, const float* __restrict__ r)
{
    const int i = blockIdx.x * 256 + threadIdx.x;
    if (i >= P_B + P_N) return;
    float nrm = sqrtf(nf[i]);
    nrm = fmaxf(nrm, 1e-12f);
    const float inv = 1.0f / nrm;
    float w = inv * inv * inv;
    if (i >= P_B) {
        const float rv = r[i - P_B];
        w *= (2.0f * rv - 1.0f);
    }
    nf[i] = w;
}

// ---------------------------------------------------------------------------
// Echo (fp8, r0-proven structure + setprio — r7/r8-verified: 59-60 us,
// MfmaUtil 46%, VGPR 60 -> 124 unified regs -> 4 waves/SIMD, no spill).
// Supertile mapping + barrier-free fragment K-loop on fp8 e4m3 operands.
// One dwordx4 per fragment-pair (K=64); two mfma_f32_16x16x32_fp8_fp8 per
// pair.  s_setprio(1) around the MFMA cluster (independent-wave regime).
// DO NOT TOUCH — byte-identical to r8.
// ---------------------------------------------------------------------------
__global__ __launch_bounds__(256, 2) void echo_pk_kernel(
    const unsigned char* __restrict__ embpk8, const float* __restrict__ fbuf,
    float* __restrict__ echo)
{
    const int tid = threadIdx.x, lane = tid & 63, wave = tid >> 6;
    const int q = lane >> 4, c = lane & 15;
    const int bid = blockIdx.x;          // 0..4095
    const int sb = bid >> 6, w = bid & 63;
    const int btile = (sb & 3) * 8 + (w & 7);    // 0..31
    const int ntile = (sb >> 2) * 8 + (w >> 3);  // 0..127
    const int row0 = btile * 128;
    const int col0 = ntile * 128;
    const int rbA0 = btile * 8 + (wave >> 1) * 4;
    const int rbB0 = 256 + ntile * 8 + (wave & 1) * 4;   // De rows start at rb 256

    const unsigned char* pa[4];
    const unsigned char* pb[4];
#pragma unroll
    for (int i = 0; i < 4; i++)
        pa[i] = embpk8 + ((size_t)(rbA0 + i) * NKTP_E * 64 + lane) * 16;
#pragma unroll
    for (int j = 0; j < 4; j++)
        pb[j] = embpk8 + ((size_t)(rbB0 + j) * NKTP_E * 64 + lane) * 16;

    f32x4 acc[4][4];
    const f32x4 zero = {0.f, 0.f, 0.f, 0.f};
#pragma unroll
    for (int i = 0; i < 4; i++)
#pragma unroll
        for (int j = 0; j < 4; j++) acc[i][j] = zero;

#pragma unroll
    for (int ktp = 0; ktp < NKTP_E; ++ktp) {
        union { uint4 v; long l[2]; } ua[4], ub[4];
#pragma unroll
        for (int i = 0; i < 4; i++) ua[i].v = *(const uint4*)(pa[i] + (size_t)ktp * 1024);
#pragma unroll
        for (int j = 0; j < 4; j++) ub[j].v = *(const uint4*)(pb[j] + (size_t)ktp * 1024);
        __builtin_amdgcn_s_setprio(1);
#pragma unroll
        for (int h = 0; h < 2; h++)
#pragma unroll
            for (int i = 0; i < 4; i++)
#pragma unroll
                for (int j = 0; j < 4; j++)
                    acc[i][j] = __builtin_amdgcn_mfma_f32_16x16x32_fp8_fp8(
                        ua[i].l[h], ub[j].l[h], acc[i][j], 0, 0, 0);
        __builtin_amdgcn_s_setprio(0);
    }

    // epilogue: cube, weight by (ind^3*r2), reduce over columns, atomicAdd rows
    const float* fX = fbuf;
    const float* fD = fbuf + P_B;
    float wc[4];
#pragma unroll
    for (int j = 0; j < 4; j++) wc[j] = fD[col0 + (wave & 1) * 64 + j * 16 + c];
    float p[4][4];
#pragma unroll
    for (int i = 0; i < 4; i++)
#pragma unroll
        for (int r = 0; r < 4; r++) p[i][r] = 0.f;
#pragma unroll
    for (int i = 0; i < 4; i++)
#pragma unroll
        for (int j = 0; j < 4; j++)
#pragma unroll
            for (int r = 0; r < 4; r++) {
                const float v = acc[i][j][r];
                const float v3 = v * v * v;
                p[i][r] = fmaf(v3, wc[j], p[i][r]);
            }
#pragma unroll
    for (int i = 0; i < 4; i++)
#pragma unroll
        for (int r = 0; r < 4; r++) {
            float s = p[i][r];
            s += __shfl_xor(s, 1);
            s += __shfl_xor(s, 2);
            s += __shfl_xor(s, 4);
            s += __shfl_xor(s, 8);
            p[i][r] = s;
        }
    if (c == 0) {
#pragma unroll
        for (int i = 0; i < 4; i++)
#pragma unroll
            for (int r = 0; r < 4; r++) {
                const int rowg = row0 + (wave >> 1) * 64 + i * 16 + q * 4 + r;
                atomicAdd(&echo[rowg], p[i][r] * fX[rowg]);
            }
    }
}

// ---------------------------------------------------------------------------
// Head: logits = echo*h_w + h_b ; preds = sigmoid(logits)
// ---------------------------------------------------------------------------
__global__ void head_kernel(const float* __restrict__ echo, const float* __restrict__ hw,
                            const float* __restrict__ hb, float* __restrict__ out)
{
    const int i = blockIdx.x * 256 + threadIdx.x;
    if (i >= P_B) return;
    const float logit = fmaf(echo[i], hw[0], hb[0]);
    out[i] = logit;
    out[P_B + i] = 1.0f / (1.0f + expf(-logit));
}

extern "C" void kernel_launch(void* const* d_in, const int* in_sizes, int n_in,
                              void* d_out, int out_size, void* d_ws, size_t ws_size,
                              hipStream_t stream)
{
    const float* X  = (const float*)d_in[0];
    const float* D  = (const float*)d_in[1];
    const float* r  = (const float*)d_in[2];
    const float* gw = (const float*)d_in[3];
    const float* gb = (const float*)d_in[4];
    const float* hw = (const float*)d_in[5];
    const float* hb = (const float*)d_in[6];
    float* out = (float*)d_out;

    char* ws = (char*)d_ws;
    const size_t xdpk_bytes   = (size_t)1280 * NKT_F * 64 * 8 * 2;    // 31,457,280
    const size_t gwpk_bytes   = (size_t)32 * NKT_F * 64 * 8 * 2;      //    786,432
    const size_t embpk8_bytes = (size_t)1280 * NKTP_E * 64 * 16;      // 10,485,760

    unsigned short* xdpk   = (unsigned short*)ws;
    unsigned short* gwpk   = (unsigned short*)(ws + xdpk_bytes);
    unsigned char*  embpk8 = (unsigned char*)(ws + xdpk_bytes + gwpk_bytes);
    float* norm2 = (float*)(ws + xdpk_bytes + gwpk_bytes + embpk8_bytes);
    float* echo = norm2 + (P_B + P_N);

    convert_pack_kernel<<<dim3(1312), 256, 0, stream>>>(X, D, gw, xdpk, gwpk, norm2);
    embed_pk_kernel<<<dim3(4, 160), 256, 0, stream>>>(xdpk, gwpk, gb, embpk8, norm2);
    finalize_kernel<<<dim3((P_B + P_N + 255) / 256), 256, 0, stream>>>(norm2, r);
    echo_pk_kernel<<<dim3(4096), 256, 0, stream>>>(embpk8, norm2, echo);
    head_kernel<<<dim3((P_B + 255) / 256), 256, 0, stream>>>(echo, hw, hb, out);
}